// Round 2
// baseline (6243.166 us; speedup 1.0000x reference)
//
#include <hip/hip_runtime.h>

// EQL network: 5-layer MLP + envelope argmax.
// Precision: f16 two-way split (hi/lo), 3 MFMAs per product (hh+hl+lh), 2^11
// pre-scale per operand so lo stays in f16 normal range -> ~2^-21 effective
// input precision, fp32 accumulate. Required because output 0 (hq) is an
// argmax-select over q.pref inner products: bf16-level error flips ~3% of
// rows' argmax and fails the 1.57e-3 threshold.
// Memory: footprint-adaptive. M-chunked pipeline (batch rows independent),
// L3/L4 N-chunked by 4 with fp32 global accumulator, L5+argmax fused in exact
// fp32 vector math reading the accumulator directly. Fits ws_size down to
// ~115 MB (Mc=128).

#define AS1 __attribute__((address_space(1)))
#define AS3 __attribute__((address_space(3)))

typedef _Float16 half8 __attribute__((ext_vector_type(8)));
typedef float floatx16 __attribute__((ext_vector_type(16)));

static constexpr float SCALE = 2048.0f;                         // 2^11
static constexpr float INV_SCALE2 = 1.0f / (2048.0f * 2048.0f); // 2^-22

// -------------------------------------------------- weight split (strided src)
// dest[n*Kpad+k] = split( src[n*srcStride + colOff + k] ) for k<Kcopy, else 0.
__global__ void split_w_kernel(const float* __restrict__ src, _Float16* __restrict__ hi,
                               _Float16* __restrict__ lo, int srcStride, int colOff,
                               int Kcopy, int Kpad) {
  int k = blockIdx.x * 256 + threadIdx.x;
  int n = blockIdx.y;
  if (k >= Kpad) return;
  float v = (k < Kcopy) ? src[(size_t)n * srcStride + colOff + k] * SCALE : 0.0f;
  _Float16 h = (_Float16)v;
  _Float16 l = (_Float16)(v - (float)h);
  size_t o = (size_t)n * Kpad + k;
  hi[o] = h;
  lo[o] = l;
}

// ------------------------------------------------------- x prep (concat+split)
__global__ void prep_x_kernel(const float* __restrict__ state, const float* __restrict__ pref,
                              _Float16* __restrict__ hi, _Float16* __restrict__ lo) {
  int k = threadIdx.x;
  int b = blockIdx.x;
  if (k >= 160) return;
  float v = 0.0f;
  if (k < 128) v = state[(size_t)b * 128 + k];
  else if (k < 132) v = pref[(size_t)b * 4 + (k - 128)];
  v *= SCALE;
  _Float16 h = (_Float16)v;
  _Float16 l = (_Float16)(v - (float)h);
  size_t o = (size_t)b * 160 + k;
  hi[o] = h;
  lo[o] = l;
}

// ------------------------------------------------------------ split-3 MFMA GEMM
// C[m][n] = sum_k A[m][k]*B[n][k]  (both K-contiguous). Tile 128x128xBK32,
// 256 thr = 4 waves, wave = 64x64 via 2x2 frags of v_mfma_f32_32x32x16_f16.
// LDS: 4 planes (Ahi,Alo,Bhi,Blo) 128x32 f16 = 32 KB, staged global_load_lds
// width=16 with XOR granule swizzle (g ^= row&3): staging writes stay linear
// (wave-uniform base + lane*16 requirement), fragment reads spread banks.
// mode 0: Ohi/Olo = split( relu(acc*2^-22 + bias[col]) * 2^11 )
// mode 1: Oacc[row*N+col] = acc*2^-22 (+ old value if accAdd)
__global__ __launch_bounds__(256) void gemm3_kernel(
    const _Float16* __restrict__ Ahi, const _Float16* __restrict__ Alo,
    const _Float16* __restrict__ Bhi, const _Float16* __restrict__ Blo,
    const float* __restrict__ bias,
    _Float16* __restrict__ Ohi, _Float16* __restrict__ Olo,
    float* __restrict__ Oacc,
    int K, int N, int mode, int accAdd) {
  __shared__ _Float16 lds[4 * 4096];  // 32 KB
  const int tid = threadIdx.x;
  const int wave = tid >> 6;
  const int lane = tid & 63;
  const int m0 = blockIdx.x * 128;
  const int n0 = blockIdx.y * 128;

  // 8 staging issues/thread: physical 16B slot p holds logical
  // (row = p>>2, granule = (p&3) ^ (row&3)) of the plane's 128x32 tile.
  const _Float16* gp[8];
  int loff[8];
#pragma unroll
  for (int j = 0; j < 8; ++j) {
    const int t = j >> 1;  // 0=Ahi 1=Alo 2=Bhi 3=Blo
    const int p = ((j & 1) << 8) + (wave << 6) + lane;
    const int r = p >> 2;
    const int g = (p & 3) ^ (r & 3);
    int row;
    const _Float16* plane;
    if (t < 2) {
      row = m0 + r;  // Mc always a multiple of 128
      plane = t ? Alo : Ahi;
    } else {
      row = n0 + r;
      if (row > N - 1) row = N - 1;  // tail N-tile: clamp (cols guarded at write)
      plane = (t == 3) ? Blo : Bhi;
    }
    gp[j] = plane + (size_t)row * K + 8 * g;
    loff[j] = t * 4096 + (((j & 1) << 8) + (wave << 6)) * 8;  // wave-uniform
  }

  const int wm = wave >> 1, wn = wave & 1;
  floatx16 acc[2][2];
#pragma unroll
  for (int i = 0; i < 2; ++i)
#pragma unroll
    for (int j = 0; j < 2; ++j)
#pragma unroll
      for (int e = 0; e < 16; ++e) acc[i][j][e] = 0.0f;

  const int rA0 = (wm << 6) + (lane & 31);
  const int rB0 = (wn << 6) + (lane & 31);
  const int gHalf = lane >> 5;

  const int nSteps = K >> 5;
  for (int ks = 0; ks < nSteps; ++ks) {
    __syncthreads();
#pragma unroll
    for (int j = 0; j < 8; ++j) {
      __builtin_amdgcn_global_load_lds((const AS1 unsigned int*)gp[j],
                                       (AS3 unsigned int*)&lds[loff[j]], 16, 0, 0);
      gp[j] += 32;
    }
    __syncthreads();  // implies vmcnt(0) drain -> staged data visible
#pragma unroll
    for (int kh = 0; kh < 2; ++kh) {
      half8 ah[2], al[2], bh[2], bl[2];
#pragma unroll
      for (int i = 0; i < 2; ++i) {
        int rA = rA0 + (i << 5);
        int sA = (rA << 2) + (((kh << 1) + gHalf) ^ (rA & 3));
        ah[i] = *(const half8*)&lds[sA << 3];
        al[i] = *(const half8*)&lds[4096 + (sA << 3)];
        int rB = rB0 + (i << 5);
        int sB = (rB << 2) + (((kh << 1) + gHalf) ^ (rB & 3));
        bh[i] = *(const half8*)&lds[8192 + (sB << 3)];
        bl[i] = *(const half8*)&lds[12288 + (sB << 3)];
      }
#pragma unroll
      for (int i = 0; i < 2; ++i)
#pragma unroll
        for (int j = 0; j < 2; ++j) {
          acc[i][j] = __builtin_amdgcn_mfma_f32_32x32x16_f16(ah[i], bh[j], acc[i][j], 0, 0, 0);
          acc[i][j] = __builtin_amdgcn_mfma_f32_32x32x16_f16(ah[i], bl[j], acc[i][j], 0, 0, 0);
          acc[i][j] = __builtin_amdgcn_mfma_f32_32x32x16_f16(al[i], bh[j], acc[i][j], 0, 0, 0);
        }
    }
  }

  // C/D layout: col = lane&31, row = (e&3) + 8*(e>>2) + 4*(lane>>5)  [m74/m101]
#pragma unroll
  for (int i = 0; i < 2; ++i)
#pragma unroll
    for (int j = 0; j < 2; ++j)
#pragma unroll
      for (int e = 0; e < 16; ++e) {
        int row = m0 + (wm << 6) + (i << 5) + ((e & 3) + ((e >> 2) << 3) + ((lane >> 5) << 2));
        int col = n0 + (wn << 6) + (j << 5) + (lane & 31);
        if (col < N) {
          float v = acc[i][j][e] * INV_SCALE2;
          size_t o = (size_t)row * N + col;
          if (mode == 0) {
            v = fmaxf(v + bias[col], 0.0f) * SCALE;
            _Float16 h = (_Float16)v;
            _Float16 l = (_Float16)(v - (float)h);
            Ohi[o] = h;
            Olo[o] = l;
          } else {
            if (accAdd) v += Oacc[o];
            Oacc[o] = v;
          }
        }
      }
}

// ----------------------- L5 head + envelope argmax, exact fp32 (reads fp32 ACC)
// Per block: 4 rows. h = relu(ACC+b4) staged in LDS; q = h @ wq^T + bq; then
// ip[a] = q[4a..4a+3].pref, first-tie argmax, hq select. Writes q and hq.
__global__ __launch_bounds__(256) void l5_finish_kernel(
    const float* __restrict__ acc4, const float* __restrict__ b4,
    const float* __restrict__ wq, const float* __restrict__ bq,
    const float* __restrict__ pref, float* __restrict__ out, int rowBase) {
  __shared__ __align__(16) float hbuf[4 * 4224];  // 67.6 KB
  __shared__ float qbuf[4 * 64];
  __shared__ float ipbuf[4 * 16];
  const int t = threadIdx.x;
  const int r0 = blockIdx.x * 4;  // chunk-local row base
#pragma unroll
  for (int r = 0; r < 4; ++r) {
    const float* src = acc4 + (size_t)(r0 + r) * 4224;
    for (int i = t; i < 4224; i += 256) hbuf[r * 4224 + i] = fmaxf(src[i] + b4[i], 0.0f);
  }
  __syncthreads();
  const int r = t >> 6, o = t & 63;
  const float* wrow = wq + (size_t)o * 4224;
  const float* hrow = &hbuf[r * 4224];
  float s = 0.0f;
  for (int k = 0; k < 4224; k += 4) {
    float4 h = *(const float4*)&hrow[k];
    float4 w = *(const float4*)&wrow[k];
    s += h.x * w.x + h.y * w.y + h.z * w.z + h.w * w.w;
  }
  s += bq[o];
  qbuf[r * 64 + o] = s;
  int grow = rowBase + r0 + r;
  out[32768 + (size_t)grow * 64 + o] = s;
  __syncthreads();
  if (t < 64) {
    int rr = t >> 4, a = t & 15;
    int g2 = rowBase + r0 + rr;
    float ip = 0.0f;
#pragma unroll
    for (int j = 0; j < 4; ++j) ip += qbuf[rr * 64 + a * 4 + j] * pref[(size_t)g2 * 4 + j];
    ipbuf[rr * 16 + a] = ip;
  }
  __syncthreads();
  if (t < 4) {
    int g2 = rowBase + r0 + t;
    float best = ipbuf[t * 16];
    int ba = 0;
#pragma unroll
    for (int a = 1; a < 16; ++a) {
      float v = ipbuf[t * 16 + a];
      if (v > best) { best = v; ba = a; }  // strict > == first-tie jnp.argmax
    }
#pragma unroll
    for (int j = 0; j < 4; ++j) out[(size_t)g2 * 4 + j] = qbuf[t * 64 + ba * 4 + j];
  }
}

// ------------------------------------------------------------------- launcher
extern "C" void kernel_launch(void* const* d_in, const int* in_sizes, int n_in,
                              void* d_out, int out_size, void* d_ws, size_t ws_size,
                              hipStream_t stream) {
  const float* state = (const float*)d_in[0];
  const float* pref = (const float*)d_in[1];
  const float* w1 = (const float*)d_in[2];
  const float* b1 = (const float*)d_in[3];
  const float* w2 = (const float*)d_in[4];
  const float* b2 = (const float*)d_in[5];
  const float* w3 = (const float*)d_in[6];
  const float* b3 = (const float*)d_in[7];
  const float* w4 = (const float*)d_in[8];
  const float* b4 = (const float*)d_in[9];
  const float* wq = (const float*)d_in[10];
  const float* bq = (const float*)d_in[11];

  // ---- workspace layout (all slabs 256B-aligned by construction)
  char* ws = (char*)d_ws;
  size_t off = 0;
  auto take = [&](size_t bytes) {
    size_t r = off;
    off += (bytes + 255) & ~(size_t)255;
    return r;
  };
  const size_t oW1h = take((size_t)2112 * 160 * 2);
  const size_t oW1l = take((size_t)2112 * 160 * 2);
  const size_t oW2h = take((size_t)4224 * 2112 * 2);
  const size_t oW2l = take((size_t)4224 * 2112 * 2);
  const size_t oW3h = take((size_t)2112 * 4224 * 2);  // quarter-chunk of W3
  const size_t oW3l = take((size_t)2112 * 4224 * 2);
  const size_t oW4h = take((size_t)4224 * 2112 * 2);  // quarter K-slice of W4
  const size_t oW4l = take((size_t)4224 * 2112 * 2);
  const size_t fixed = off;

  // per-row bytes: X 640 + H1 8448 + H2 16896 + H3 8448 + ACC 16896 = 51328
  int Mc = 8192;
  while (Mc > 128 && fixed + (size_t)Mc * 51328 + 4096 > ws_size) Mc >>= 1;

  const size_t oXh = take((size_t)Mc * 160 * 2);
  const size_t oXl = take((size_t)Mc * 160 * 2);
  const size_t oH1h = take((size_t)Mc * 2112 * 2);
  const size_t oH1l = take((size_t)Mc * 2112 * 2);
  const size_t oH2h = take((size_t)Mc * 4224 * 2);
  const size_t oH2l = take((size_t)Mc * 4224 * 2);
  const size_t oH3h = take((size_t)Mc * 2112 * 2);
  const size_t oH3l = take((size_t)Mc * 2112 * 2);
  const size_t oACC = take((size_t)Mc * 4224 * 4);

  _Float16* W1h = (_Float16*)(ws + oW1h);
  _Float16* W1l = (_Float16*)(ws + oW1l);
  _Float16* W2h = (_Float16*)(ws + oW2h);
  _Float16* W2l = (_Float16*)(ws + oW2l);
  _Float16* W3h = (_Float16*)(ws + oW3h);
  _Float16* W3l = (_Float16*)(ws + oW3l);
  _Float16* W4h = (_Float16*)(ws + oW4h);
  _Float16* W4l = (_Float16*)(ws + oW4l);
  _Float16* Xh = (_Float16*)(ws + oXh);
  _Float16* Xl = (_Float16*)(ws + oXl);
  _Float16* H1h = (_Float16*)(ws + oH1h);
  _Float16* H1l = (_Float16*)(ws + oH1l);
  _Float16* H2h = (_Float16*)(ws + oH2h);
  _Float16* H2l = (_Float16*)(ws + oH2l);
  _Float16* H3h = (_Float16*)(ws + oH3h);
  _Float16* H3l = (_Float16*)(ws + oH3l);
  float* ACC = (float*)(ws + oACC);

  // persistent weight splits (W1 padded 132->160)
  split_w_kernel<<<dim3(1, 2112), 256, 0, stream>>>(w1, W1h, W1l, 132, 0, 132, 160);
  split_w_kernel<<<dim3(9, 4224), 256, 0, stream>>>(w2, W2h, W2l, 2112, 0, 2112, 2112);

  const int NC = 8192 / Mc;
  const int GX = Mc / 128;
  for (int mc = 0; mc < NC; ++mc) {
    const float* st = state + (size_t)mc * Mc * 128;
    const float* pf = pref + (size_t)mc * Mc * 4;
    prep_x_kernel<<<dim3(Mc), 192, 0, stream>>>(st, pf, Xh, Xl);
    // L1: [Mc,160] x [2112,160]
    gemm3_kernel<<<dim3(GX, 17), 256, 0, stream>>>(Xh, Xl, W1h, W1l, b1, H1h, H1l,
                                                   nullptr, 160, 2112, 0, 0);
    // L2: K=2112 -> N=4224
    gemm3_kernel<<<dim3(GX, 33), 256, 0, stream>>>(H1h, H1l, W2h, W2l, b2, H2h, H2l,
                                                   nullptr, 2112, 4224, 0, 0);
    // L3/L4 fused over 4 N-chunks of H3 (2112 each); ACC accumulates L4.
    for (int c = 0; c < 4; ++c) {
      split_w_kernel<<<dim3(17, 2112), 256, 0, stream>>>(w3 + (size_t)c * 2112 * 4224, W3h,
                                                         W3l, 4224, 0, 4224, 4224);
      split_w_kernel<<<dim3(9, 4224), 256, 0, stream>>>(w4, W4h, W4l, 8448, c * 2112, 2112,
                                                        2112);
      gemm3_kernel<<<dim3(GX, 17), 256, 0, stream>>>(H2h, H2l, W3h, W3l, b3 + c * 2112,
                                                     H3h, H3l, nullptr, 4224, 2112, 0, 0);
      gemm3_kernel<<<dim3(GX, 33), 256, 0, stream>>>(H3h, H3l, W4h, W4l, nullptr, nullptr,
                                                     nullptr, ACC, 2112, 4224, 1, c);
    }
    // L5 + envelope argmax in exact fp32 (relu+b4 fused on ACC read)
    l5_finish_kernel<<<dim3(Mc / 4), 256, 0, stream>>>(ACC, b4, wq, bq, pref,
                                                       (float*)d_out, mc * Mc);
  }
}

// Round 3
// 5396.501 us; speedup vs baseline: 1.1569x; 1.1569x over previous
//
#include <hip/hip_runtime.h>

// EQL network: 5-layer MLP + envelope argmax.
// Precision: f16 two-way split (hi/lo), 3 MFMAs per product (hh+hl+lh), 2^11
// pre-scale per operand so lo stays in f16 normal range -> ~2^-21 effective
// input precision, fp32 accumulate. Required because output 0 (hq) is an
// argmax-select over q.pref inner products.
// R2 -> R3: removed the latency-bound fp32 l5_finish (was 965 us, top kernel,
// VALUBusy 10%): L4 last-chunk epilogue (mode 2) now finalizes relu+b4 and
// writes split H4 planes over the dead H2 slab; L5 runs through the MFMA GEMM
// with split-K=4; a tiny reduce+argmax kernel finishes.

#define AS1 __attribute__((address_space(1)))
#define AS3 __attribute__((address_space(3)))

typedef _Float16 half8 __attribute__((ext_vector_type(8)));
typedef float floatx16 __attribute__((ext_vector_type(16)));

static constexpr float SCALE = 2048.0f;                         // 2^11
static constexpr float INV_SCALE2 = 1.0f / (2048.0f * 2048.0f); // 2^-22

// -------------------------------------------------- weight split (strided src)
__global__ void split_w_kernel(const float* __restrict__ src, _Float16* __restrict__ hi,
                               _Float16* __restrict__ lo, int srcStride, int colOff,
                               int Kcopy, int Kpad) {
  int k = blockIdx.x * 256 + threadIdx.x;
  int n = blockIdx.y;
  if (k >= Kpad) return;
  float v = (k < Kcopy) ? src[(size_t)n * srcStride + colOff + k] * SCALE : 0.0f;
  _Float16 h = (_Float16)v;
  _Float16 l = (_Float16)(v - (float)h);
  size_t o = (size_t)n * Kpad + k;
  hi[o] = h;
  lo[o] = l;
}

// ------------------------------------------------------- x prep (concat+split)
__global__ void prep_x_kernel(const float* __restrict__ state, const float* __restrict__ pref,
                              _Float16* __restrict__ hi, _Float16* __restrict__ lo) {
  int k = threadIdx.x;
  int b = blockIdx.x;
  if (k >= 160) return;
  float v = 0.0f;
  if (k < 128) v = state[(size_t)b * 128 + k];
  else if (k < 132) v = pref[(size_t)b * 4 + (k - 128)];
  v *= SCALE;
  _Float16 h = (_Float16)v;
  _Float16 l = (_Float16)(v - (float)h);
  size_t o = (size_t)b * 160 + k;
  hi[o] = h;
  lo[o] = l;
}

// ------------------------------------------------------------ split-3 MFMA GEMM
// C[m][n] = sum_k A[m][k]*B[n][k]  (both K-contiguous). Tile 128x128xBK32,
// 256 thr = 4 waves, wave = 64x64 via 2x2 frags of v_mfma_f32_32x32x16_f16.
// LDS: 4 planes (Ahi,Alo,Bhi,Blo) 128x32 f16 = 32 KB, staged global_load_lds
// width=16 with XOR granule swizzle (g ^= row&3).
// K range per block: [blockIdx.z*kPerZ, +kPerZ).
// mode 0: Ohi/Olo = split( relu(acc*2^-22 + bias[col]) * 2^11 )
// mode 1: Oacc[(bz*Mrows+row)*N+col] = acc*2^-22 (+ old if accAdd)
// mode 2: v = acc*2^-22 + Oacc[row*N+col]; Ohi/Olo = split(relu(v+bias)*2^11)
__global__ __launch_bounds__(256) void gemm3_kernel(
    const _Float16* __restrict__ Ahi, const _Float16* __restrict__ Alo,
    const _Float16* __restrict__ Bhi, const _Float16* __restrict__ Blo,
    const float* __restrict__ bias,
    _Float16* __restrict__ Ohi, _Float16* __restrict__ Olo,
    float* __restrict__ Oacc,
    int K, int N, int kPerZ, int mode, int accAdd, int Mrows) {
  __shared__ _Float16 lds[4 * 4096];  // 32 KB
  const int tid = threadIdx.x;
  const int wave = tid >> 6;
  const int lane = tid & 63;
  const int m0 = blockIdx.x * 128;
  const int n0 = blockIdx.y * 128;
  const int kBeg = blockIdx.z * kPerZ;

  // 8 staging issues/thread: physical 16B slot p holds logical
  // (row = p>>2, granule = (p&3) ^ (row&3)) of the plane's 128x32 tile.
  const _Float16* gp[8];
  int loff[8];
#pragma unroll
  for (int j = 0; j < 8; ++j) {
    const int t = j >> 1;  // 0=Ahi 1=Alo 2=Bhi 3=Blo
    const int p = ((j & 1) << 8) + (wave << 6) + lane;
    const int r = p >> 2;
    const int g = (p & 3) ^ (r & 3);
    int row;
    const _Float16* plane;
    if (t < 2) {
      row = m0 + r;  // Mc always a multiple of 128
      plane = t ? Alo : Ahi;
    } else {
      row = n0 + r;
      if (row > N - 1) row = N - 1;  // tail N-tile: clamp (cols guarded at write)
      plane = (t == 3) ? Blo : Bhi;
    }
    gp[j] = plane + (size_t)row * K + kBeg + 8 * g;
    loff[j] = t * 4096 + (((j & 1) << 8) + (wave << 6)) * 8;  // wave-uniform
  }

  const int wm = wave >> 1, wn = wave & 1;
  floatx16 acc[2][2];
#pragma unroll
  for (int i = 0; i < 2; ++i)
#pragma unroll
    for (int j = 0; j < 2; ++j)
#pragma unroll
      for (int e = 0; e < 16; ++e) acc[i][j][e] = 0.0f;

  const int rA0 = (wm << 6) + (lane & 31);
  const int rB0 = (wn << 6) + (lane & 31);
  const int gHalf = lane >> 5;

  const int nSteps = kPerZ >> 5;
  for (int ks = 0; ks < nSteps; ++ks) {
    __syncthreads();
#pragma unroll
    for (int j = 0; j < 8; ++j) {
      __builtin_amdgcn_global_load_lds((const AS1 unsigned int*)gp[j],
                                       (AS3 unsigned int*)&lds[loff[j]], 16, 0, 0);
      gp[j] += 32;
    }
    __syncthreads();  // implies vmcnt(0) drain -> staged data visible
#pragma unroll
    for (int kh = 0; kh < 2; ++kh) {
      half8 ah[2], al[2], bh[2], bl[2];
#pragma unroll
      for (int i = 0; i < 2; ++i) {
        int rA = rA0 + (i << 5);
        int sA = (rA << 2) + (((kh << 1) + gHalf) ^ (rA & 3));
        ah[i] = *(const half8*)&lds[sA << 3];
        al[i] = *(const half8*)&lds[4096 + (sA << 3)];
        int rB = rB0 + (i << 5);
        int sB = (rB << 2) + (((kh << 1) + gHalf) ^ (rB & 3));
        bh[i] = *(const half8*)&lds[8192 + (sB << 3)];
        bl[i] = *(const half8*)&lds[12288 + (sB << 3)];
      }
#pragma unroll
      for (int i = 0; i < 2; ++i)
#pragma unroll
        for (int j = 0; j < 2; ++j) {
          acc[i][j] = __builtin_amdgcn_mfma_f32_32x32x16_f16(ah[i], bh[j], acc[i][j], 0, 0, 0);
          acc[i][j] = __builtin_amdgcn_mfma_f32_32x32x16_f16(ah[i], bl[j], acc[i][j], 0, 0, 0);
          acc[i][j] = __builtin_amdgcn_mfma_f32_32x32x16_f16(al[i], bh[j], acc[i][j], 0, 0, 0);
        }
    }
  }

  // C/D layout: col = lane&31, row = (e&3) + 8*(e>>2) + 4*(lane>>5)  [m74/m101]
#pragma unroll
  for (int i = 0; i < 2; ++i)
#pragma unroll
    for (int j = 0; j < 2; ++j)
#pragma unroll
      for (int e = 0; e < 16; ++e) {
        int row = m0 + (wm << 6) + (i << 5) + ((e & 3) + ((e >> 2) << 3) + ((lane >> 5) << 2));
        int col = n0 + (wn << 6) + (j << 5) + (lane & 31);
        if (col < N) {
          float v = acc[i][j][e] * INV_SCALE2;
          if (mode == 0) {
            size_t o = (size_t)row * N + col;
            v = fmaxf(v + bias[col], 0.0f) * SCALE;
            _Float16 h = (_Float16)v;
            _Float16 l = (_Float16)(v - (float)h);
            Ohi[o] = h;
            Olo[o] = l;
          } else if (mode == 1) {
            size_t o = ((size_t)blockIdx.z * Mrows + row) * N + col;
            if (accAdd) v += Oacc[o];
            Oacc[o] = v;
          } else {  // mode 2: finalize L4 -> split H4 planes
            size_t o = (size_t)row * N + col;
            v += Oacc[o];
            v = fmaxf(v + bias[col], 0.0f) * SCALE;
            _Float16 h = (_Float16)v;
            _Float16 l = (_Float16)(v - (float)h);
            Ohi[o] = h;
            Olo[o] = l;
          }
        }
      }
}

// --------------------------------- reduce split-K partials + envelope argmax
// One thread per row. QP layout [4][Mc][64] fp32.
__global__ __launch_bounds__(128) void finish_kernel(
    const float* __restrict__ part, const float* __restrict__ bq,
    const float* __restrict__ pref, float* __restrict__ out, int rowBase, int Mc) {
  int b = blockIdx.x * 128 + threadIdx.x;  // chunk-local row
  if (b >= Mc) return;
  float q[64];
#pragma unroll
  for (int o4 = 0; o4 < 16; ++o4) {
    float4 s = *(const float4*)&part[(size_t)b * 64 + o4 * 4];
    float4 s1 = *(const float4*)&part[(size_t)(Mc + b) * 64 + o4 * 4];
    float4 s2 = *(const float4*)&part[(size_t)(2 * Mc + b) * 64 + o4 * 4];
    float4 s3 = *(const float4*)&part[(size_t)(3 * Mc + b) * 64 + o4 * 4];
    float4 bb = *(const float4*)&bq[o4 * 4];
    q[o4 * 4 + 0] = s.x + s1.x + s2.x + s3.x + bb.x;
    q[o4 * 4 + 1] = s.y + s1.y + s2.y + s3.y + bb.y;
    q[o4 * 4 + 2] = s.z + s1.z + s2.z + s3.z + bb.z;
    q[o4 * 4 + 3] = s.w + s1.w + s2.w + s3.w + bb.w;
  }
  int g = rowBase + b;
  float* qout = out + 32768 + (size_t)g * 64;
#pragma unroll
  for (int o4 = 0; o4 < 16; ++o4)
    *(float4*)&qout[o4 * 4] = make_float4(q[o4 * 4], q[o4 * 4 + 1], q[o4 * 4 + 2], q[o4 * 4 + 3]);
  float p0 = pref[(size_t)g * 4 + 0], p1 = pref[(size_t)g * 4 + 1];
  float p2 = pref[(size_t)g * 4 + 2], p3 = pref[(size_t)g * 4 + 3];
  float best = q[0] * p0 + q[1] * p1 + q[2] * p2 + q[3] * p3;
  int ba = 0;
#pragma unroll
  for (int a = 1; a < 16; ++a) {
    float ip = q[4 * a] * p0 + q[4 * a + 1] * p1 + q[4 * a + 2] * p2 + q[4 * a + 3] * p3;
    if (ip > best) { best = ip; ba = a; }  // strict > == first-tie jnp.argmax
  }
  *(float4*)&out[(size_t)g * 4] =
      make_float4(q[4 * ba], q[4 * ba + 1], q[4 * ba + 2], q[4 * ba + 3]);
}

// ------------------------------------------------------------------- launcher
extern "C" void kernel_launch(void* const* d_in, const int* in_sizes, int n_in,
                              void* d_out, int out_size, void* d_ws, size_t ws_size,
                              hipStream_t stream) {
  const float* state = (const float*)d_in[0];
  const float* pref = (const float*)d_in[1];
  const float* w1 = (const float*)d_in[2];
  const float* b1 = (const float*)d_in[3];
  const float* w2 = (const float*)d_in[4];
  const float* b2 = (const float*)d_in[5];
  const float* w3 = (const float*)d_in[6];
  const float* b3 = (const float*)d_in[7];
  const float* w4 = (const float*)d_in[8];
  const float* b4 = (const float*)d_in[9];
  const float* wq = (const float*)d_in[10];
  const float* bq = (const float*)d_in[11];

  char* ws = (char*)d_ws;
  size_t off = 0;
  auto take = [&](size_t bytes) {
    size_t r = off;
    off += (bytes + 255) & ~(size_t)255;
    return r;
  };
  const size_t oW1h = take((size_t)2112 * 160 * 2);
  const size_t oW1l = take((size_t)2112 * 160 * 2);
  const size_t oW2h = take((size_t)4224 * 2112 * 2);
  const size_t oW2l = take((size_t)4224 * 2112 * 2);
  const size_t oW3h = take((size_t)2112 * 4224 * 2);  // quarter N-chunk of W3
  const size_t oW3l = take((size_t)2112 * 4224 * 2);
  const size_t oW4h = take((size_t)4224 * 2112 * 2);  // quarter K-slice of W4
  const size_t oW4l = take((size_t)4224 * 2112 * 2);
  const size_t oW5h = take((size_t)64 * 4224 * 2);
  const size_t oW5l = take((size_t)64 * 4224 * 2);
  const size_t fixed = off;

  // per-row bytes: X 640 + H1 8448 + H2 16896 + H3 8448 + ACC 16896 = 51328
  // (H4 overlays H2; QP overlays H1)
  int Mc = 8192;
  while (Mc > 128 && fixed + (size_t)Mc * 51328 + 4096 > ws_size) Mc >>= 1;

  const size_t oXh = take((size_t)Mc * 160 * 2);
  const size_t oXl = take((size_t)Mc * 160 * 2);
  const size_t oH1h = take((size_t)Mc * 2112 * 2);
  const size_t oH1l = take((size_t)Mc * 2112 * 2);
  const size_t oH2h = take((size_t)Mc * 4224 * 2);
  const size_t oH2l = take((size_t)Mc * 4224 * 2);
  const size_t oH3h = take((size_t)Mc * 2112 * 2);
  const size_t oH3l = take((size_t)Mc * 2112 * 2);
  const size_t oACC = take((size_t)Mc * 4224 * 4);

  _Float16* W1h = (_Float16*)(ws + oW1h);
  _Float16* W1l = (_Float16*)(ws + oW1l);
  _Float16* W2h = (_Float16*)(ws + oW2h);
  _Float16* W2l = (_Float16*)(ws + oW2l);
  _Float16* W3h = (_Float16*)(ws + oW3h);
  _Float16* W3l = (_Float16*)(ws + oW3l);
  _Float16* W4h = (_Float16*)(ws + oW4h);
  _Float16* W4l = (_Float16*)(ws + oW4l);
  _Float16* W5h = (_Float16*)(ws + oW5h);
  _Float16* W5l = (_Float16*)(ws + oW5l);
  _Float16* Xh = (_Float16*)(ws + oXh);
  _Float16* Xl = (_Float16*)(ws + oXl);
  _Float16* H1h = (_Float16*)(ws + oH1h);
  _Float16* H1l = (_Float16*)(ws + oH1l);
  _Float16* H2h = (_Float16*)(ws + oH2h);
  _Float16* H2l = (_Float16*)(ws + oH2l);
  _Float16* H3h = (_Float16*)(ws + oH3h);
  _Float16* H3l = (_Float16*)(ws + oH3l);
  float* ACC = (float*)(ws + oACC);
  _Float16* H4h = H2h;           // overlays H2 (dead after last L3)
  _Float16* H4l = H2l;
  float* QP = (float*)(ws + oH1h);  // overlays H1 (dead after L2)

  // persistent weight splits (W1 padded 132->160)
  split_w_kernel<<<dim3(1, 2112), 256, 0, stream>>>(w1, W1h, W1l, 132, 0, 132, 160);
  split_w_kernel<<<dim3(9, 4224), 256, 0, stream>>>(w2, W2h, W2l, 2112, 0, 2112, 2112);
  split_w_kernel<<<dim3(17, 64), 256, 0, stream>>>(wq, W5h, W5l, 4224, 0, 4224, 4224);

  const int NC = 8192 / Mc;
  const int GX = Mc / 128;
  for (int mc = 0; mc < NC; ++mc) {
    const float* st = state + (size_t)mc * Mc * 128;
    const float* pf = pref + (size_t)mc * Mc * 4;
    prep_x_kernel<<<dim3(Mc), 192, 0, stream>>>(st, pf, Xh, Xl);
    // L1: [Mc,160] x [2112,160]
    gemm3_kernel<<<dim3(GX, 17), 256, 0, stream>>>(Xh, Xl, W1h, W1l, b1, H1h, H1l,
                                                   nullptr, 160, 2112, 160, 0, 0, Mc);
    // L2: K=2112 -> N=4224
    gemm3_kernel<<<dim3(GX, 33), 256, 0, stream>>>(H1h, H1l, W2h, W2l, b2, H2h, H2l,
                                                   nullptr, 2112, 4224, 2112, 0, 0, Mc);
    // L3/L4 fused over 4 N-chunks of H3 (2112 each); ACC accumulates L4;
    // last chunk finalizes relu+b4 and writes split H4 planes (over H2).
    for (int c = 0; c < 4; ++c) {
      split_w_kernel<<<dim3(17, 2112), 256, 0, stream>>>(w3 + (size_t)c * 2112 * 4224, W3h,
                                                         W3l, 4224, 0, 4224, 4224);
      split_w_kernel<<<dim3(9, 4224), 256, 0, stream>>>(w4, W4h, W4l, 8448, c * 2112, 2112,
                                                        2112);
      gemm3_kernel<<<dim3(GX, 17), 256, 0, stream>>>(H2h, H2l, W3h, W3l, b3 + c * 2112,
                                                     H3h, H3l, nullptr, 4224, 2112, 4224,
                                                     0, 0, Mc);
      if (c < 3) {
        gemm3_kernel<<<dim3(GX, 33), 256, 0, stream>>>(H3h, H3l, W4h, W4l, nullptr, nullptr,
                                                       nullptr, ACC, 2112, 4224, 2112, 1,
                                                       c > 0 ? 1 : 0, Mc);
      } else {
        gemm3_kernel<<<dim3(GX, 33), 256, 0, stream>>>(H3h, H3l, W4h, W4l, b4, H4h, H4l,
                                                       ACC, 2112, 4224, 2112, 2, 0, Mc);
      }
    }
    // L5: [Mc,4224] x [64,4224], split-K=4 -> QP fp32 partials
    gemm3_kernel<<<dim3(GX, 1, 4), 256, 0, stream>>>(H4h, H4l, W5h, W5l, nullptr, nullptr,
                                                     nullptr, QP, 4224, 64, 1056, 1, 0, Mc);
    // reduce partials + bq, write q, envelope argmax -> hq
    finish_kernel<<<dim3(Mc / 128), 128, 0, stream>>>(QP, bq, pref, (float*)d_out,
                                                      mc * Mc, Mc);
  }
}

// Round 4
// 5192.471 us; speedup vs baseline: 1.2023x; 1.0393x over previous
//
#include <hip/hip_runtime.h>

// EQL network: 5-layer MLP + envelope argmax.
// Precision: f16 two-way split (hi/lo), 3 MFMAs per product (hh+hl+lh), 2^11
// pre-scale per operand so lo stays in f16 normal range -> ~2^-21 effective
// input precision, fp32 accumulate. Required because output 0 (hq) is an
// argmax-select over q.pref inner products.
// R3 -> R4: fixed LDS bank-conflict swizzle. Bank group of a 16B slot is
// slot%8; old swizzle (g ^ (r&3)) made read slots cover only 4 of 8 groups
// per 32-lane half-wave (8-way conflict, SQ_LDS_BANK_CONFLICT=1.07e8,
// +11.6 cyc/ds_read_b128). New swizzle (g ^ ((r>>1)&3)) covers all 8 groups
// exactly 4x per half-wave -> conflict-free. Staging writes unchanged
// (64 consecutive slots); only the global granule permutation changes.

#define AS1 __attribute__((address_space(1)))
#define AS3 __attribute__((address_space(3)))

typedef _Float16 half8 __attribute__((ext_vector_type(8)));
typedef float floatx16 __attribute__((ext_vector_type(16)));

static constexpr float SCALE = 2048.0f;                         // 2^11
static constexpr float INV_SCALE2 = 1.0f / (2048.0f * 2048.0f); // 2^-22

// -------------------------------------------------- weight split (strided src)
__global__ void split_w_kernel(const float* __restrict__ src, _Float16* __restrict__ hi,
                               _Float16* __restrict__ lo, int srcStride, int colOff,
                               int Kcopy, int Kpad) {
  int k = blockIdx.x * 256 + threadIdx.x;
  int n = blockIdx.y;
  if (k >= Kpad) return;
  float v = (k < Kcopy) ? src[(size_t)n * srcStride + colOff + k] * SCALE : 0.0f;
  _Float16 h = (_Float16)v;
  _Float16 l = (_Float16)(v - (float)h);
  size_t o = (size_t)n * Kpad + k;
  hi[o] = h;
  lo[o] = l;
}

// ------------------------------------------------------- x prep (concat+split)
__global__ void prep_x_kernel(const float* __restrict__ state, const float* __restrict__ pref,
                              _Float16* __restrict__ hi, _Float16* __restrict__ lo) {
  int k = threadIdx.x;
  int b = blockIdx.x;
  if (k >= 160) return;
  float v = 0.0f;
  if (k < 128) v = state[(size_t)b * 128 + k];
  else if (k < 132) v = pref[(size_t)b * 4 + (k - 128)];
  v *= SCALE;
  _Float16 h = (_Float16)v;
  _Float16 l = (_Float16)(v - (float)h);
  size_t o = (size_t)b * 160 + k;
  hi[o] = h;
  lo[o] = l;
}

// ------------------------------------------------------------ split-3 MFMA GEMM
// C[m][n] = sum_k A[m][k]*B[n][k]  (both K-contiguous). Tile 128x128xBK32,
// 256 thr = 4 waves, wave = 64x64 via 2x2 frags of v_mfma_f32_32x32x16_f16.
// LDS: 4 planes (Ahi,Alo,Bhi,Blo) 128x32 f16 = 32 KB, staged global_load_lds
// width=16. Swizzle: logical (row r, granule g) lives at slot 4r+(g^((r>>1)&3))
// -> slot%8 (the 4-bank group) is uniform over any 32 consecutive rows at
// fixed g, AND over the 64 consecutive slots a staging wave writes.
// K range per block: [blockIdx.z*kPerZ, +kPerZ).
// mode 0: Ohi/Olo = split( relu(acc*2^-22 + bias[col]) * 2^11 )
// mode 1: Oacc[(bz*Mrows+row)*N+col] = acc*2^-22 (+ old if accAdd)
// mode 2: v = acc*2^-22 + Oacc[row*N+col]; Ohi/Olo = split(relu(v+bias)*2^11)
__global__ __launch_bounds__(256) void gemm3_kernel(
    const _Float16* __restrict__ Ahi, const _Float16* __restrict__ Alo,
    const _Float16* __restrict__ Bhi, const _Float16* __restrict__ Blo,
    const float* __restrict__ bias,
    _Float16* __restrict__ Ohi, _Float16* __restrict__ Olo,
    float* __restrict__ Oacc,
    int K, int N, int kPerZ, int mode, int accAdd, int Mrows) {
  __shared__ _Float16 lds[4 * 4096];  // 32 KB
  const int tid = threadIdx.x;
  const int wave = tid >> 6;
  const int lane = tid & 63;
  const int m0 = blockIdx.x * 128;
  const int n0 = blockIdx.y * 128;
  const int kBeg = blockIdx.z * kPerZ;

  // 8 staging issues/thread: physical 16B slot p holds logical
  // (row = p>>2, granule = (p&3) ^ ((row>>1)&3)) of the plane's 128x32 tile.
  const _Float16* gp[8];
  int loff[8];
#pragma unroll
  for (int j = 0; j < 8; ++j) {
    const int t = j >> 1;  // 0=Ahi 1=Alo 2=Bhi 3=Blo
    const int p = ((j & 1) << 8) + (wave << 6) + lane;
    const int r = p >> 2;
    const int g = (p & 3) ^ ((r >> 1) & 3);
    int row;
    const _Float16* plane;
    if (t < 2) {
      row = m0 + r;  // Mc always a multiple of 128
      plane = t ? Alo : Ahi;
    } else {
      row = n0 + r;
      if (row > N - 1) row = N - 1;  // tail N-tile: clamp (cols guarded at write)
      plane = (t == 3) ? Blo : Bhi;
    }
    gp[j] = plane + (size_t)row * K + kBeg + 8 * g;
    loff[j] = t * 4096 + (((j & 1) << 8) + (wave << 6)) * 8;  // wave-uniform
  }

  const int wm = wave >> 1, wn = wave & 1;
  floatx16 acc[2][2];
#pragma unroll
  for (int i = 0; i < 2; ++i)
#pragma unroll
    for (int j = 0; j < 2; ++j)
#pragma unroll
      for (int e = 0; e < 16; ++e) acc[i][j][e] = 0.0f;

  const int rA0 = (wm << 6) + (lane & 31);
  const int rB0 = (wn << 6) + (lane & 31);
  const int gHalf = lane >> 5;

  const int nSteps = kPerZ >> 5;
  for (int ks = 0; ks < nSteps; ++ks) {
    __syncthreads();
#pragma unroll
    for (int j = 0; j < 8; ++j) {
      __builtin_amdgcn_global_load_lds((const AS1 unsigned int*)gp[j],
                                       (AS3 unsigned int*)&lds[loff[j]], 16, 0, 0);
      gp[j] += 32;
    }
    __syncthreads();  // implies vmcnt(0) drain -> staged data visible
#pragma unroll
    for (int kh = 0; kh < 2; ++kh) {
      half8 ah[2], al[2], bh[2], bl[2];
#pragma unroll
      for (int i = 0; i < 2; ++i) {
        int rA = rA0 + (i << 5);
        int sA = (rA << 2) + (((kh << 1) + gHalf) ^ ((rA >> 1) & 3));
        ah[i] = *(const half8*)&lds[sA << 3];
        al[i] = *(const half8*)&lds[4096 + (sA << 3)];
        int rB = rB0 + (i << 5);
        int sB = (rB << 2) + (((kh << 1) + gHalf) ^ ((rB >> 1) & 3));
        bh[i] = *(const half8*)&lds[8192 + (sB << 3)];
        bl[i] = *(const half8*)&lds[12288 + (sB << 3)];
      }
#pragma unroll
      for (int i = 0; i < 2; ++i)
#pragma unroll
        for (int j = 0; j < 2; ++j) {
          acc[i][j] = __builtin_amdgcn_mfma_f32_32x32x16_f16(ah[i], bh[j], acc[i][j], 0, 0, 0);
          acc[i][j] = __builtin_amdgcn_mfma_f32_32x32x16_f16(ah[i], bl[j], acc[i][j], 0, 0, 0);
          acc[i][j] = __builtin_amdgcn_mfma_f32_32x32x16_f16(al[i], bh[j], acc[i][j], 0, 0, 0);
        }
    }
  }

  // C/D layout: col = lane&31, row = (e&3) + 8*(e>>2) + 4*(lane>>5)  [m74/m101]
#pragma unroll
  for (int i = 0; i < 2; ++i)
#pragma unroll
    for (int j = 0; j < 2; ++j)
#pragma unroll
      for (int e = 0; e < 16; ++e) {
        int row = m0 + (wm << 6) + (i << 5) + ((e & 3) + ((e >> 2) << 3) + ((lane >> 5) << 2));
        int col = n0 + (wn << 6) + (j << 5) + (lane & 31);
        if (col < N) {
          float v = acc[i][j][e] * INV_SCALE2;
          if (mode == 0) {
            size_t o = (size_t)row * N + col;
            v = fmaxf(v + bias[col], 0.0f) * SCALE;
            _Float16 h = (_Float16)v;
            _Float16 l = (_Float16)(v - (float)h);
            Ohi[o] = h;
            Olo[o] = l;
          } else if (mode == 1) {
            size_t o = ((size_t)blockIdx.z * Mrows + row) * N + col;
            if (accAdd) v += Oacc[o];
            Oacc[o] = v;
          } else {  // mode 2: finalize L4 -> split H4 planes
            size_t o = (size_t)row * N + col;
            v += Oacc[o];
            v = fmaxf(v + bias[col], 0.0f) * SCALE;
            _Float16 h = (_Float16)v;
            _Float16 l = (_Float16)(v - (float)h);
            Ohi[o] = h;
            Olo[o] = l;
          }
        }
      }
}

// --------------------------------- reduce split-K partials + envelope argmax
// One thread per row. QP layout [4][Mc][64] fp32.
__global__ __launch_bounds__(128) void finish_kernel(
    const float* __restrict__ part, const float* __restrict__ bq,
    const float* __restrict__ pref, float* __restrict__ out, int rowBase, int Mc) {
  int b = blockIdx.x * 128 + threadIdx.x;  // chunk-local row
  if (b >= Mc) return;
  float q[64];
#pragma unroll
  for (int o4 = 0; o4 < 16; ++o4) {
    float4 s = *(const float4*)&part[(size_t)b * 64 + o4 * 4];
    float4 s1 = *(const float4*)&part[(size_t)(Mc + b) * 64 + o4 * 4];
    float4 s2 = *(const float4*)&part[(size_t)(2 * Mc + b) * 64 + o4 * 4];
    float4 s3 = *(const float4*)&part[(size_t)(3 * Mc + b) * 64 + o4 * 4];
    float4 bb = *(const float4*)&bq[o4 * 4];
    q[o4 * 4 + 0] = s.x + s1.x + s2.x + s3.x + bb.x;
    q[o4 * 4 + 1] = s.y + s1.y + s2.y + s3.y + bb.y;
    q[o4 * 4 + 2] = s.z + s1.z + s2.z + s3.z + bb.z;
    q[o4 * 4 + 3] = s.w + s1.w + s2.w + s3.w + bb.w;
  }
  int g = rowBase + b;
  float* qout = out + 32768 + (size_t)g * 64;
#pragma unroll
  for (int o4 = 0; o4 < 16; ++o4)
    *(float4*)&qout[o4 * 4] = make_float4(q[o4 * 4], q[o4 * 4 + 1], q[o4 * 4 + 2], q[o4 * 4 + 3]);
  float p0 = pref[(size_t)g * 4 + 0], p1 = pref[(size_t)g * 4 + 1];
  float p2 = pref[(size_t)g * 4 + 2], p3 = pref[(size_t)g * 4 + 3];
  float best = q[0] * p0 + q[1] * p1 + q[2] * p2 + q[3] * p3;
  int ba = 0;
#pragma unroll
  for (int a = 1; a < 16; ++a) {
    float ip = q[4 * a] * p0 + q[4 * a + 1] * p1 + q[4 * a + 2] * p2 + q[4 * a + 3] * p3;
    if (ip > best) { best = ip; ba = a; }  // strict > == first-tie jnp.argmax
  }
  *(float4*)&out[(size_t)g * 4] =
      make_float4(q[4 * ba], q[4 * ba + 1], q[4 * ba + 2], q[4 * ba + 3]);
}

// ------------------------------------------------------------------- launcher
extern "C" void kernel_launch(void* const* d_in, const int* in_sizes, int n_in,
                              void* d_out, int out_size, void* d_ws, size_t ws_size,
                              hipStream_t stream) {
  const float* state = (const float*)d_in[0];
  const float* pref = (const float*)d_in[1];
  const float* w1 = (const float*)d_in[2];
  const float* b1 = (const float*)d_in[3];
  const float* w2 = (const float*)d_in[4];
  const float* b2 = (const float*)d_in[5];
  const float* w3 = (const float*)d_in[6];
  const float* b3 = (const float*)d_in[7];
  const float* w4 = (const float*)d_in[8];
  const float* b4 = (const float*)d_in[9];
  const float* wq = (const float*)d_in[10];
  const float* bq = (const float*)d_in[11];

  char* ws = (char*)d_ws;
  size_t off = 0;
  auto take = [&](size_t bytes) {
    size_t r = off;
    off += (bytes + 255) & ~(size_t)255;
    return r;
  };
  const size_t oW1h = take((size_t)2112 * 160 * 2);
  const size_t oW1l = take((size_t)2112 * 160 * 2);
  const size_t oW2h = take((size_t)4224 * 2112 * 2);
  const size_t oW2l = take((size_t)4224 * 2112 * 2);
  const size_t oW3h = take((size_t)2112 * 4224 * 2);  // quarter N-chunk of W3
  const size_t oW3l = take((size_t)2112 * 4224 * 2);
  const size_t oW4h = take((size_t)4224 * 2112 * 2);  // quarter K-slice of W4
  const size_t oW4l = take((size_t)4224 * 2112 * 2);
  const size_t oW5h = take((size_t)64 * 4224 * 2);
  const size_t oW5l = take((size_t)64 * 4224 * 2);
  const size_t fixed = off;

  // per-row bytes: X 640 + H1 8448 + H2 16896 + H3 8448 + ACC 16896 = 51328
  // (H4 overlays H2; QP overlays H1)
  int Mc = 8192;
  while (Mc > 128 && fixed + (size_t)Mc * 51328 + 4096 > ws_size) Mc >>= 1;

  const size_t oXh = take((size_t)Mc * 160 * 2);
  const size_t oXl = take((size_t)Mc * 160 * 2);
  const size_t oH1h = take((size_t)Mc * 2112 * 2);
  const size_t oH1l = take((size_t)Mc * 2112 * 2);
  const size_t oH2h = take((size_t)Mc * 4224 * 2);
  const size_t oH2l = take((size_t)Mc * 4224 * 2);
  const size_t oH3h = take((size_t)Mc * 2112 * 2);
  const size_t oH3l = take((size_t)Mc * 2112 * 2);
  const size_t oACC = take((size_t)Mc * 4224 * 4);

  _Float16* W1h = (_Float16*)(ws + oW1h);
  _Float16* W1l = (_Float16*)(ws + oW1l);
  _Float16* W2h = (_Float16*)(ws + oW2h);
  _Float16* W2l = (_Float16*)(ws + oW2l);
  _Float16* W3h = (_Float16*)(ws + oW3h);
  _Float16* W3l = (_Float16*)(ws + oW3l);
  _Float16* W4h = (_Float16*)(ws + oW4h);
  _Float16* W4l = (_Float16*)(ws + oW4l);
  _Float16* W5h = (_Float16*)(ws + oW5h);
  _Float16* W5l = (_Float16*)(ws + oW5l);
  _Float16* Xh = (_Float16*)(ws + oXh);
  _Float16* Xl = (_Float16*)(ws + oXl);
  _Float16* H1h = (_Float16*)(ws + oH1h);
  _Float16* H1l = (_Float16*)(ws + oH1l);
  _Float16* H2h = (_Float16*)(ws + oH2h);
  _Float16* H2l = (_Float16*)(ws + oH2l);
  _Float16* H3h = (_Float16*)(ws + oH3h);
  _Float16* H3l = (_Float16*)(ws + oH3l);
  float* ACC = (float*)(ws + oACC);
  _Float16* H4h = H2h;           // overlays H2 (dead after last L3)
  _Float16* H4l = H2l;
  float* QP = (float*)(ws + oH1h);  // overlays H1 (dead after L2)

  // persistent weight splits (W1 padded 132->160)
  split_w_kernel<<<dim3(1, 2112), 256, 0, stream>>>(w1, W1h, W1l, 132, 0, 132, 160);
  split_w_kernel<<<dim3(9, 4224), 256, 0, stream>>>(w2, W2h, W2l, 2112, 0, 2112, 2112);
  split_w_kernel<<<dim3(17, 64), 256, 0, stream>>>(wq, W5h, W5l, 4224, 0, 4224, 4224);

  const int NC = 8192 / Mc;
  const int GX = Mc / 128;
  for (int mc = 0; mc < NC; ++mc) {
    const float* st = state + (size_t)mc * Mc * 128;
    const float* pf = pref + (size_t)mc * Mc * 4;
    prep_x_kernel<<<dim3(Mc), 192, 0, stream>>>(st, pf, Xh, Xl);
    // L1: [Mc,160] x [2112,160]
    gemm3_kernel<<<dim3(GX, 17), 256, 0, stream>>>(Xh, Xl, W1h, W1l, b1, H1h, H1l,
                                                   nullptr, 160, 2112, 160, 0, 0, Mc);
    // L2: K=2112 -> N=4224
    gemm3_kernel<<<dim3(GX, 33), 256, 0, stream>>>(H1h, H1l, W2h, W2l, b2, H2h, H2l,
                                                   nullptr, 2112, 4224, 2112, 0, 0, Mc);
    // L3/L4 fused over 4 N-chunks of H3 (2112 each); ACC accumulates L4;
    // last chunk finalizes relu+b4 and writes split H4 planes (over H2).
    for (int c = 0; c < 4; ++c) {
      split_w_kernel<<<dim3(17, 2112), 256, 0, stream>>>(w3 + (size_t)c * 2112 * 4224, W3h,
                                                         W3l, 4224, 0, 4224, 4224);
      split_w_kernel<<<dim3(9, 4224), 256, 0, stream>>>(w4, W4h, W4l, 8448, c * 2112, 2112,
                                                        2112);
      gemm3_kernel<<<dim3(GX, 17), 256, 0, stream>>>(H2h, H2l, W3h, W3l, b3 + c * 2112,
                                                     H3h, H3l, nullptr, 4224, 2112, 4224,
                                                     0, 0, Mc);
      if (c < 3) {
        gemm3_kernel<<<dim3(GX, 33), 256, 0, stream>>>(H3h, H3l, W4h, W4l, nullptr, nullptr,
                                                       nullptr, ACC, 2112, 4224, 2112, 1,
                                                       c > 0 ? 1 : 0, Mc);
      } else {
        gemm3_kernel<<<dim3(GX, 33), 256, 0, stream>>>(H3h, H3l, W4h, W4l, b4, H4h, H4l,
                                                       ACC, 2112, 4224, 2112, 2, 0, Mc);
      }
    }
    // L5: [Mc,4224] x [64,4224], split-K=4 -> QP fp32 partials
    gemm3_kernel<<<dim3(GX, 1, 4), 256, 0, stream>>>(H4h, H4l, W5h, W5l, nullptr, nullptr,
                                                     nullptr, QP, 4224, 64, 1056, 1, 0, Mc);
    // reduce partials + bq, write q, envelope argmax -> hq
    finish_kernel<<<dim3(Mc / 128), 128, 0, stream>>>(QP, bq, pref, (float*)d_out,
                                                      mc * Mc, Mc);
  }
}